// Round 9
// baseline (65.168 us; speedup 1.0000x reference)
//
#include <hip/hip_runtime.h>
#include <hip/hip_bf16.h>
#include <math.h>

#define B_ROWS 4096
#define NTOT   8192
#define DDIM   256
#define CSCALE 1.6986436f      // sqrt(2*log2(e)); zn scaled so A.B = 2*log2(e)*cos
#define NPART  8

typedef __attribute__((ext_vector_type(8))) short short8;   // 8 bf16
typedef __attribute__((ext_vector_type(4))) float f32x4;

#define GLB(p) ((const __attribute__((address_space(1))) void*)(p))
#define LDSP(p) ((__attribute__((address_space(3))) void*)(p))

static __device__ inline unsigned short f2bf(float x) {
    union { float f; unsigned u; } v; v.f = x;
    unsigned r = v.u + 0x7fffu + ((v.u >> 16) & 1u);  // RNE
    return (unsigned short)(r >> 16);
}

// ---- kernel 1: normalize (scaled bf16, PRE-SWIZZLED rows) + pos-pair sims + zero partials ----
// zn row r stores logical 16B-chunk c at physical chunk c^(r&15). XOR is an
// involution: A-loads and LDS-tile reads apply the same XOR; staging reads linear.
__global__ __launch_bounds__(256) void norm_kernel(
        const float* __restrict__ zi, const float* __restrict__ zj,
        unsigned short* __restrict__ zn, float* __restrict__ simpos,
        float* __restrict__ parts) {
    int pair = blockIdx.x * 4 + (threadIdx.x >> 6);
    int lane = threadIdx.x & 63;
    float4 vi = reinterpret_cast<const float4*>(zi + (size_t)pair * DDIM)[lane];
    float4 vj = reinterpret_cast<const float4*>(zj + (size_t)pair * DDIM)[lane];
    float ssi = vi.x*vi.x + vi.y*vi.y + vi.z*vi.z + vi.w*vi.w;
    float ssj = vj.x*vj.x + vj.y*vj.y + vj.z*vj.z + vj.w*vj.w;
    float dij = vi.x*vj.x + vi.y*vj.y + vi.z*vj.z + vi.w*vj.w;
    #pragma unroll
    for (int o = 32; o > 0; o >>= 1) {
        ssi += __shfl_xor(ssi, o);
        ssj += __shfl_xor(ssj, o);
        dij += __shfl_xor(dij, o);
    }
    float invi = 1.0f / fmaxf(sqrtf(ssi), 1e-8f);
    float invj = 1.0f / fmaxf(sqrtf(ssj), 1e-8f);
    float si = CSCALE * invi, sj = CSCALE * invj;
    ushort4 hi4, hj4;
    hi4.x = f2bf(vi.x * si); hi4.y = f2bf(vi.y * si);
    hi4.z = f2bf(vi.z * si); hi4.w = f2bf(vi.w * si);
    hj4.x = f2bf(vj.x * sj); hj4.y = f2bf(vj.y * sj);
    hj4.z = f2bf(vj.z * sj); hj4.w = f2bf(vj.w * sj);
    // pre-swizzled write: logical chunk (lane>>1), half (lane&1); rows pair and
    // pair+4096 share (r&15) == (pair&15) since 4096 % 16 == 0.
    int swz = ((lane >> 1) ^ (pair & 15)) * 16 + (lane & 1) * 8;
    unsigned char* ri = (unsigned char*)zn + (size_t)pair * 512;
    unsigned char* rj = (unsigned char*)zn + (size_t)(pair + B_ROWS) * 512;
    *reinterpret_cast<ushort4*>(ri + swz) = hi4;
    *reinterpret_cast<ushort4*>(rj + swz) = hj4;
    if (lane == 0) simpos[pair] = 2.0f * dij * invi * invj;   // logits = cos/tau
    if (blockIdx.x < 256) parts[blockIdx.x * 256 + threadIdx.x] = 0.0f;  // zero 64K floats
}

// ---- kernel 2 body: 128 rows x 128 cols = 4 pipelined 32-col units ----
// 4 waves x 32 A-rows (a[2][8] = 64 VGPR). Double-buffered LDS (2 x 16 KB),
// global_load_lds width-16 staging issued BEFORE compute of current buffer:
// one barrier per unit, staging latency hidden under MFMA+exp phase.
template<bool CROSS>
static __device__ __forceinline__ void sim_body(
        const unsigned char* __restrict__ znb, float* __restrict__ part,
        unsigned char* __restrict__ tile, float (* __restrict__ csum_lds)[128],
        int waveRow, int c0base) {
    int tid  = threadIdx.x;
    int wid  = tid >> 6;
    int lane = tid & 63;
    int l15  = lane & 15;
    int l4   = lane >> 4;

    // A fragments (16x16x32: row = l15, k-chunk = 4m + l4), XOR-deswizzled
    short8 a[2][8];
    #pragma unroll
    for (int rs = 0; rs < 2; ++rs) {
        const unsigned char* ap = znb + (size_t)(waveRow + rs * 16 + l15) * 512;
        #pragma unroll
        for (int m = 0; m < 8; ++m)
            a[rs][m] = *reinterpret_cast<const short8*>(ap + (((4 * m + l4) ^ l15) << 4));
    }

    // async-stage one 32-col unit (16 KB) into buf: linear LDS, linear global
    auto STAGE = [&](unsigned char* buf, int c0) {
        #pragma unroll
        for (int p = 0; p < 4; ++p) {
            int id = p * 256 + tid;
            int tr = id >> 5, ck = id & 31;
            __builtin_amdgcn_global_load_lds(
                GLB(znb + (size_t)(c0 + tr) * 512 + ck * 16),
                LDSP(buf + id * 16), 16, 0, 0);
        }
    };

    float rsum[2][4] = {{0.f,0.f,0.f,0.f},{0.f,0.f,0.f,0.f}};

    STAGE(tile, c0base);          // prologue: fill buf0
    __syncthreads();              // drains vmcnt (compiler emits full waitcnt)

    #pragma unroll
    for (int u = 0; u < 4; ++u) {
        unsigned char* cur = tile + (u & 1) * (32 * 512);
        if (u < 3) STAGE(tile + ((u + 1) & 1) * (32 * 512), c0base + (u + 1) * 32);

        int c0u = c0base + u * 32;
        #pragma unroll
        for (int sub = 0; sub < 2; ++sub) {
            const unsigned char* bbase = cur + (size_t)(sub * 16 + l15) * 512;
            f32x4 acc0 = {0.f,0.f,0.f,0.f}, acc1 = {0.f,0.f,0.f,0.f};
            #pragma unroll
            for (int m = 0; m < 8; ++m) {   // one b-frag feeds both rowsets (ILP x2)
                short8 bf = *reinterpret_cast<const short8*>(
                    bbase + (((4 * m + l4) ^ l15) << 4));
                acc0 = __builtin_amdgcn_mfma_f32_16x16x32_bf16(a[0][m], bf, acc0, 0, 0, 0);
                acc1 = __builtin_amdgcn_mfma_f32_16x16x32_bf16(a[1][m], bf, acc1, 0, 0, 0);
            }
            int gcol = c0u + sub * 16 + l15;
            float cs = 0.0f;
            #pragma unroll
            for (int j = 0; j < 4; ++j) {
                float e0 = exp2f(acc0[j]);   // zn pre-scaled: acc = 2*log2e*cos
                float e1 = exp2f(acc1[j]);
                if (CROSS) {
                    int g0 = waveRow + l4 * 4 + j;        // rowset 0
                    e0 = (gcol > g0) ? e0 : 0.0f;
                    e1 = (gcol > g0 + 16) ? e1 : 0.0f;    // rowset 1
                }
                rsum[0][j] += e0;
                rsum[1][j] += e1;
                cs += e0 + e1;
            }
            cs += __shfl_xor(cs, 16);
            cs += __shfl_xor(cs, 32);
            if (lane < 16) csum_lds[wid][u * 32 + sub * 16 + l15] = cs;
        }
        __syncthreads();   // all waves done reading cur; next buf's loads drained
    }

    // ---- flush rows: reduce across the 16 col-lanes, one atomic per row ----
    #pragma unroll
    for (int rs = 0; rs < 2; ++rs)
        #pragma unroll
        for (int j = 0; j < 4; ++j) {
            float s = rsum[rs][j];
            #pragma unroll
            for (int m = 8; m >= 1; m >>= 1) s += __shfl_xor(s, m);
            if (l15 == 0)
                atomicAdd(&part[waveRow + rs * 16 + l4 * 4 + j], s);
        }

    // ---- flush cols: sum 4 waves' slices, one atomic per col ----
    if (tid < 128) {
        float s = csum_lds[0][tid] + csum_lds[1][tid]
                + csum_lds[2][tid] + csum_lds[3][tid];
        atomicAdd(&part[c0base + tid], s);
    }
}

// 2080 uniform blocks: strip s (64 strips of 128 rows) has 64-s blocks of 128
// cols starting at the diagonal; prefix(s) = 64s - s(s-1)/2. rel==0 => CROSS.
__global__ __launch_bounds__(256, 3) void sim_kernel(
        const unsigned short* __restrict__ zn, float* __restrict__ parts) {
    __shared__ __align__(16) unsigned char tile[2 * 32 * 512];   // 32 KB dbuf
    __shared__ float csum_lds[4][128];                           // 2 KB

    int b = blockIdx.x;
    int s = (int)(64.5f - sqrtf(4160.25f - 2.0f * (float)b));
    if (s < 0) s = 0;
    if (s > 63) s = 63;
    while (s > 0 && b < 64 * s - (s * (s - 1)) / 2) --s;
    while (b >= 64 * (s + 1) - ((s + 1) * s) / 2) ++s;
    int rel = b - (64 * s - (s * (s - 1)) / 2);

    int waveRow = s * 128 + (threadIdx.x >> 6) * 32;
    int c0base  = (s + rel) * 128;
    float* part = parts + (size_t)(b & (NPART - 1)) * NTOT;
    const unsigned char* znb = (const unsigned char*)zn;

    if (rel == 0) sim_body<true >(znb, part, tile, csum_lds, waveRow, c0base);
    else          sim_body<false>(znb, part, tile, csum_lds, waveRow, c0base);
}

// ---- kernel 3: loss = sum_r (log(sum_p parts[p][r]) - simpos[r % B]) / N ----
__global__ __launch_bounds__(1024) void finalize_kernel(
        const float* __restrict__ parts, const float* __restrict__ simpos,
        float* __restrict__ out) {
    __shared__ float red[16];
    int tid = threadIdx.x;
    float acc = 0.0f;
    #pragma unroll
    for (int rr = 0; rr < 8; ++rr) {
        int r = rr * 1024 + tid;
        float s = 0.0f;
        #pragma unroll
        for (int p = 0; p < NPART; ++p) s += parts[p * NTOT + r];
        acc += logf(s) - simpos[r & (B_ROWS - 1)];
    }
    #pragma unroll
    for (int o = 32; o > 0; o >>= 1) acc += __shfl_xor(acc, o);
    if ((tid & 63) == 0) red[tid >> 6] = acc;
    __syncthreads();
    if (tid == 0) {
        float t = 0.0f;
        #pragma unroll
        for (int w = 0; w < 16; ++w) t += red[w];
        out[0] = t / (float)NTOT;
    }
}

extern "C" void kernel_launch(void* const* d_in, const int* in_sizes, int n_in,
                              void* d_out, int out_size, void* d_ws, size_t ws_size,
                              hipStream_t stream) {
    const float* zi = (const float*)d_in[0];
    const float* zj = (const float*)d_in[1];
    float* out = (float*)d_out;

    unsigned short* zn = (unsigned short*)d_ws;                        // 4 MB
    float* parts  = (float*)((char*)d_ws + (size_t)NTOT * DDIM * 2);   // 256 KB
    float* simpos = parts + NPART * NTOT;                              // 16 KB

    norm_kernel<<<B_ROWS / 4, 256, 0, stream>>>(zi, zj, zn, simpos, parts);
    sim_kernel<<<2080, 256, 0, stream>>>(zn, parts);
    finalize_kernel<<<1, 1024, 0, stream>>>(parts, simpos, out);
}

// Round 10
// 63.591 us; speedup vs baseline: 1.0248x; 1.0248x over previous
//
#include <hip/hip_runtime.h>
#include <hip/hip_bf16.h>
#include <math.h>

#define B_ROWS 4096
#define NTOT   8192
#define DDIM   256
#define CSCALE 1.6986436f      // sqrt(2*log2(e)); zn scaled so A.B = 2*log2(e)*cos
#define NPART  8

typedef __attribute__((ext_vector_type(8))) short short8;   // 8 bf16
typedef __attribute__((ext_vector_type(4))) float f32x4;

static __device__ inline unsigned short f2bf(float x) {
    union { float f; unsigned u; } v; v.f = x;
    unsigned r = v.u + 0x7fffu + ((v.u >> 16) & 1u);  // RNE
    return (unsigned short)(r >> 16);
}

// ---- kernel 1: fused normalize (scaled bf16) + positive-pair sims + partials zeroing ----
__global__ __launch_bounds__(256) void norm_kernel(
        const float* __restrict__ zi, const float* __restrict__ zj,
        unsigned short* __restrict__ zn, float* __restrict__ simpos,
        float* __restrict__ parts) {
    int pair = blockIdx.x * 4 + (threadIdx.x >> 6);
    int lane = threadIdx.x & 63;
    float4 vi = reinterpret_cast<const float4*>(zi + (size_t)pair * DDIM)[lane];
    float4 vj = reinterpret_cast<const float4*>(zj + (size_t)pair * DDIM)[lane];
    float ssi = vi.x*vi.x + vi.y*vi.y + vi.z*vi.z + vi.w*vi.w;
    float ssj = vj.x*vj.x + vj.y*vj.y + vj.z*vj.z + vj.w*vj.w;
    float dij = vi.x*vj.x + vi.y*vj.y + vi.z*vj.z + vi.w*vj.w;
    #pragma unroll
    for (int o = 32; o > 0; o >>= 1) {
        ssi += __shfl_xor(ssi, o);
        ssj += __shfl_xor(ssj, o);
        dij += __shfl_xor(dij, o);
    }
    float invi = 1.0f / fmaxf(sqrtf(ssi), 1e-8f);
    float invj = 1.0f / fmaxf(sqrtf(ssj), 1e-8f);
    float si = CSCALE * invi, sj = CSCALE * invj;
    ushort4 hi4, hj4;
    hi4.x = f2bf(vi.x * si); hi4.y = f2bf(vi.y * si);
    hi4.z = f2bf(vi.z * si); hi4.w = f2bf(vi.w * si);
    hj4.x = f2bf(vj.x * sj); hj4.y = f2bf(vj.y * sj);
    hj4.z = f2bf(vj.z * sj); hj4.w = f2bf(vj.w * sj);
    *reinterpret_cast<ushort4*>(zn + (size_t)pair * DDIM + lane * 4) = hi4;
    *reinterpret_cast<ushort4*>(zn + (size_t)(pair + B_ROWS) * DDIM + lane * 4) = hj4;
    if (lane == 0) simpos[pair] = 2.0f * dij * invi * invj;   // logits = cos/tau
    if (blockIdx.x < 256) parts[blockIdx.x * 256 + threadIdx.x] = 0.0f;  // zero 64K floats
}

// ---- kernel 2 body: 128 rows x 128 cols = 4 pipelined 32-col units ----
// 4 waves x 32 A-rows (a[2][8] = 64 VGPR). T14 split staging: DSWRITE(u) ->
// barrier -> GLOAD(u+1) issued -> compute(u); loads land during MFMA+exp.
// One barrier per unit; LDS ping-pong (2 x 16 KB).
template<bool CROSS>
static __device__ __forceinline__ void sim_body(
        const unsigned short* __restrict__ zn, float* __restrict__ part,
        unsigned char* __restrict__ tile, float (* __restrict__ csum_lds)[128],
        int waveRow, int c0base) {
    int tid  = threadIdx.x;
    int wid  = tid >> 6;
    int lane = tid & 63;
    int l15  = lane & 15;
    int l4   = lane >> 4;

    // A fragments (16x16x32 layout: row = l15, k = m*32 + l4*8)
    short8 a[2][8];
    #pragma unroll
    for (int rs = 0; rs < 2; ++rs) {
        const unsigned short* ap = zn + (size_t)(waveRow + rs * 16 + l15) * DDIM;
        #pragma unroll
        for (int m = 0; m < 8; ++m)
            a[rs][m] = *reinterpret_cast<const short8*>(ap + m * 32 + l4 * 8);
    }

    // 32-col unit = 16 KB = 1024 x 16B chunks / 256 thr = 4 per thread
    auto GLOAD = [&](uint4* t, int c0) {
        #pragma unroll
        for (int p = 0; p < 4; ++p) {
            int id = p * 256 + tid;
            int tr = id >> 5, ck = id & 31;
            t[p] = *reinterpret_cast<const uint4*>(
                zn + (size_t)(c0 + tr) * DDIM + ck * 8);
        }
    };
    auto DSWRITE = [&](unsigned char* buf, const uint4* t) {
        #pragma unroll
        for (int p = 0; p < 4; ++p) {
            int id = p * 256 + tid;
            int tr = id >> 5, ck = id & 31;
            *reinterpret_cast<uint4*>(buf + tr * 512 + ((ck ^ (tr & 15)) << 4)) = t[p];
        }
    };

    float rsum[2][4] = {{0.f,0.f,0.f,0.f},{0.f,0.f,0.f,0.f}};
    uint4 t0[4], t1[4];

    GLOAD(t0, c0base);            // prologue: unit 0 into regs

    #pragma unroll
    for (int u = 0; u < 4; ++u) {
        unsigned char* cur = tile + (u & 1) * (32 * 512);
        DSWRITE(cur, (u & 1) ? t1 : t0);        // write unit u (waits its vmcnt)
        __syncthreads();                        // buf[u&1] visible to all waves
        if (u < 3) GLOAD((u & 1) ? t0 : t1, c0base + (u + 1) * 32);  // in flight

        int c0u = c0base + u * 32;
        #pragma unroll
        for (int sub = 0; sub < 2; ++sub) {
            const unsigned char* bbase = cur + (size_t)(sub * 16 + l15) * 512;
            f32x4 acc0 = {0.f,0.f,0.f,0.f}, acc1 = {0.f,0.f,0.f,0.f};
            __builtin_amdgcn_s_setprio(1);
            #pragma unroll
            for (int m = 0; m < 8; ++m) {   // one b-frag feeds both rowsets (ILP x2)
                short8 bf = *reinterpret_cast<const short8*>(
                    bbase + (((4 * m + l4) ^ l15) << 4));
                acc0 = __builtin_amdgcn_mfma_f32_16x16x32_bf16(a[0][m], bf, acc0, 0, 0, 0);
                acc1 = __builtin_amdgcn_mfma_f32_16x16x32_bf16(a[1][m], bf, acc1, 0, 0, 0);
            }
            __builtin_amdgcn_s_setprio(0);
            int gcol = c0u + sub * 16 + l15;
            float cs = 0.0f;
            #pragma unroll
            for (int j = 0; j < 4; ++j) {
                float e0 = exp2f(acc0[j]);   // zn pre-scaled: acc = 2*log2e*cos
                float e1 = exp2f(acc1[j]);
                if (CROSS) {
                    int g0 = waveRow + l4 * 4 + j;        // rowset 0
                    e0 = (gcol > g0) ? e0 : 0.0f;
                    e1 = (gcol > g0 + 16) ? e1 : 0.0f;    // rowset 1
                }
                rsum[0][j] += e0;
                rsum[1][j] += e1;
                cs += e0 + e1;
            }
            cs += __shfl_xor(cs, 16);
            cs += __shfl_xor(cs, 32);
            if (lane < 16) csum_lds[wid][u * 32 + sub * 16 + l15] = cs;
        }
        // no trailing barrier: next DSWRITE targets the other buffer, and the
        // barrier at the top of iter u+1 orders compute(u) before any wave's
        // DSWRITE(u+2) overwrite of this buffer.
    }

    // ---- flush rows: reduce across the 16 col-lanes, one atomic per row ----
    #pragma unroll
    for (int rs = 0; rs < 2; ++rs)
        #pragma unroll
        for (int j = 0; j < 4; ++j) {
            float s = rsum[rs][j];
            #pragma unroll
            for (int m = 8; m >= 1; m >>= 1) s += __shfl_xor(s, m);
            if (l15 == 0)
                atomicAdd(&part[waveRow + rs * 16 + l4 * 4 + j], s);
        }

    // ---- flush cols: sum 4 waves' slices, one atomic per col ----
    __syncthreads();
    if (tid < 128) {
        float s = csum_lds[0][tid] + csum_lds[1][tid]
                + csum_lds[2][tid] + csum_lds[3][tid];
        atomicAdd(&part[c0base + tid], s);
    }
}

// 2080 uniform blocks: strip s (64 strips of 128 rows) has 64-s blocks of 128
// cols starting at the diagonal; prefix(s) = 64s - s(s-1)/2. rel==0 => CROSS.
__global__ __launch_bounds__(256, 3) void sim_kernel(
        const unsigned short* __restrict__ zn, float* __restrict__ parts) {
    __shared__ __align__(16) unsigned char tile[2 * 32 * 512];   // 32 KB ping-pong
    __shared__ float csum_lds[4][128];                           // 2 KB

    int b = blockIdx.x;
    int s = (int)(64.5f - sqrtf(4160.25f - 2.0f * (float)b));
    if (s < 0) s = 0;
    if (s > 63) s = 63;
    while (s > 0 && b < 64 * s - (s * (s - 1)) / 2) --s;
    while (b >= 64 * (s + 1) - ((s + 1) * s) / 2) ++s;
    int rel = b - (64 * s - (s * (s - 1)) / 2);

    int waveRow = s * 128 + (threadIdx.x >> 6) * 32;
    int c0base  = (s + rel) * 128;
    float* part = parts + (size_t)(b & (NPART - 1)) * NTOT;

    if (rel == 0) sim_body<true >(zn, part, tile, csum_lds, waveRow, c0base);
    else          sim_body<false>(zn, part, tile, csum_lds, waveRow, c0base);
}

// ---- kernel 3: loss = sum_r (log(sum_p parts[p][r]) - simpos[r % B]) / N ----
__global__ __launch_bounds__(1024) void finalize_kernel(
        const float* __restrict__ parts, const float* __restrict__ simpos,
        float* __restrict__ out) {
    __shared__ float red[16];
    int tid = threadIdx.x;
    float acc = 0.0f;
    #pragma unroll
    for (int rr = 0; rr < 8; ++rr) {
        int r = rr * 1024 + tid;
        float s = 0.0f;
        #pragma unroll
        for (int p = 0; p < NPART; ++p) s += parts[p * NTOT + r];
        acc += logf(s) - simpos[r & (B_ROWS - 1)];
    }
    #pragma unroll
    for (int o = 32; o > 0; o >>= 1) acc += __shfl_xor(acc, o);
    if ((tid & 63) == 0) red[tid >> 6] = acc;
    __syncthreads();
    if (tid == 0) {
        float t = 0.0f;
        #pragma unroll
        for (int w = 0; w < 16; ++w) t += red[w];
        out[0] = t / (float)NTOT;
    }
}

extern "C" void kernel_launch(void* const* d_in, const int* in_sizes, int n_in,
                              void* d_out, int out_size, void* d_ws, size_t ws_size,
                              hipStream_t stream) {
    const float* zi = (const float*)d_in[0];
    const float* zj = (const float*)d_in[1];
    float* out = (float*)d_out;

    unsigned short* zn = (unsigned short*)d_ws;                        // 4 MB
    float* parts  = (float*)((char*)d_ws + (size_t)NTOT * DDIM * 2);   // 256 KB
    float* simpos = parts + NPART * NTOT;                              // 16 KB

    norm_kernel<<<B_ROWS / 4, 256, 0, stream>>>(zi, zj, zn, simpos, parts);
    sim_kernel<<<2080, 256, 0, stream>>>(zn, parts);
    finalize_kernel<<<1, 1024, 0, stream>>>(parts, simpos, out);
}